// Round 1
// 345.987 us; speedup vs baseline: 1.0280x; 1.0280x over previous
//
#include <hip/hip_runtime.h>
#include <math.h>

// Problem constants (fixed by the reference; inputs are fp32)
#define M_TOT   32400
#define CKDIM   64
#define QTOT    1620
#define QPAD    1792      // 28 q-groups x 64
#define OCDIM   1536      // O*CV = 3*512
#define TOPK    20
#define NSPLIT  81        // 32400/81 = 400 m per split
#define MSPLIT  400
#define NTILES  25        // 25 m-tiles of 16 per split
#define KQUAD   3         // keys kept per (q, split, quad)
#define KSPLIT  (4*KQUAD) // 12 keys per (q, split)
#define KEYSQ   (NSPLIT*KSPLIT)   // 972 keys per query
#define POOL    32        // approx-global pool rescored exactly

typedef __attribute__((ext_vector_type(8))) short bf16x8;  // 8 bf16 (4 VGPRs)
typedef __attribute__((ext_vector_type(4))) float f32x4;

__device__ __forceinline__ float bf2f(unsigned short u) {
    union { unsigned int i; float f; } v;
    v.i = ((unsigned int)u) << 16;
    return v.f;
}

__device__ __forceinline__ unsigned short f2bf(float f) {
    union { float f; unsigned int i; } u;
    u.f = f;
    unsigned int r = u.i + 0x7FFF + ((u.i >> 16) & 1);  // RTNE
    return (unsigned short)(r >> 16);
}

__device__ __forceinline__ float med3f(float a, float b, float c) {
#if __has_builtin(__builtin_amdgcn_fmed3f)
    return __builtin_amdgcn_fmed3f(a, b, c);
#else
    return fmaxf(fminf(a, b), fminf(fmaxf(a, b), c));
#endif
}

// Branch-free insert of x into descending-sorted 3-list (med3 chain).
#define INS3(t, x) do {                    \
    t[2] = med3f((x), t[1], t[2]);         \
    t[1] = med3f((x), t[0], t[1]);         \
    t[0] = fmaxf(t[0], (x));               \
} while (0)

#define INS8(t, x) do {                    \
    t[7] = med3f((x), t[6], t[7]);         \
    t[6] = med3f((x), t[5], t[6]);         \
    t[5] = med3f((x), t[4], t[5]);         \
    t[4] = med3f((x), t[3], t[4]);         \
    t[3] = med3f((x), t[2], t[3]);         \
    t[2] = med3f((x), t[1], t[2]);         \
    t[1] = med3f((x), t[0], t[1]);         \
    t[0] = fmaxf(t[0], (x));               \
} while (0)

// ---------------------------------------------------------------------------
// K_prep: single pass producing asq, bf16 mkT/qkT (MFMA layout), fp32
// mkTf/qkTf (contiguous rescore rows).
// ---------------------------------------------------------------------------
__global__ __launch_bounds__(256) void k_prep(const float* __restrict__ mk,
                                              const float* __restrict__ qk,
                                              float* __restrict__ asq,
                                              unsigned short* __restrict__ mkT,
                                              float* __restrict__ mkTf,
                                              unsigned short* __restrict__ qkT,
                                              float* __restrict__ qkTf) {
    int idx = blockIdx.x * 256 + threadIdx.x;
    if (idx < M_TOT) {
        const int m = idx;
        float vals[CKDIM];
        float s = 0.f;
        #pragma unroll
        for (int c = 0; c < CKDIM; ++c) {
            vals[c] = mk[(size_t)c * M_TOT + m];
            s += vals[c] * vals[c];
        }
        asq[m] = s;
        uint4* db = (uint4*)(mkT + (size_t)m * CKDIM);
        #pragma unroll
        for (int g = 0; g < 8; ++g) {
            unsigned int r[4];
            #pragma unroll
            for (int p = 0; p < 4; ++p)
                r[p] = (unsigned int)f2bf(vals[g * 8 + 2 * p])
                     | ((unsigned int)f2bf(vals[g * 8 + 2 * p + 1]) << 16);
            db[g] = make_uint4(r[0], r[1], r[2], r[3]);
        }
        float4* df = (float4*)(mkTf + (size_t)m * CKDIM);
        #pragma unroll
        for (int g = 0; g < 16; ++g)
            df[g] = make_float4(vals[4 * g], vals[4 * g + 1], vals[4 * g + 2], vals[4 * g + 3]);
    } else if (idx < M_TOT + QPAD) {
        const int q = idx - M_TOT;
        float vals[CKDIM];
        #pragma unroll
        for (int c = 0; c < CKDIM; ++c)
            vals[c] = (q < QTOT) ? qk[(size_t)c * QTOT + q] : 0.f;
        uint4* db = (uint4*)(qkT + (size_t)q * CKDIM);
        #pragma unroll
        for (int g = 0; g < 8; ++g) {
            unsigned int r[4];
            #pragma unroll
            for (int p = 0; p < 4; ++p)
                r[p] = (unsigned int)f2bf(vals[g * 8 + 2 * p])
                     | ((unsigned int)f2bf(vals[g * 8 + 2 * p + 1]) << 16);
            db[g] = make_uint4(r[0], r[1], r[2], r[3]);
        }
        float4* df = (float4*)(qkTf + (size_t)q * CKDIM);
        #pragma unroll
        for (int g = 0; g < 16; ++g)
            df[g] = make_float4(vals[4 * g], vals[4 * g + 1], vals[4 * g + 2], vals[4 * g + 3]);
    }
}

// ---------------------------------------------------------------------------
// K1: MFMA affinity scan, register-resident selection on packed keys.
// grid = (7 qquad-blocks, 81 splits), block = 256 (4 waves, one q-group
// each). The 4 waves share the same 51.2 KB mkT strip -> L1 reuse; WG
// count 2268 -> 567.
// Score = dot - 0.5*asq (monotone in affinity); key = (score & ~0x7FFF) | m.
// C/D layout (verified r3-r6): col=lane&15 (q), row=quad*4+reg (m).
// Per lane: top-3 per (its q-column qt, its m-quad) via med3 chain.
// ---------------------------------------------------------------------------
__global__ __launch_bounds__(256) void k_topk_mfma(const unsigned short* __restrict__ mkT,
                                                   const unsigned short* __restrict__ qkT,
                                                   const float* __restrict__ asq,
                                                   float* __restrict__ pkeys) {
    const int lane = threadIdx.x & 63;
    const int wave = threadIdx.x >> 6;
    const int l15  = lane & 15;
    const int quad = lane >> 4;
    const int q_base = (blockIdx.x * 4 + wave) * 64;
    const int sp     = blockIdx.y;
    const int m_base = sp * MSPLIT;

    bf16x8 bF[4][2];
    #pragma unroll
    for (int qt = 0; qt < 4; ++qt) {
        const unsigned short* p = qkT + (size_t)(q_base + qt * 16 + l15) * CKDIM + quad * 8;
        bF[qt][0] = *(const bf16x8*)(p);
        bF[qt][1] = *(const bf16x8*)(p + 32);
    }

    float key3[4][KQUAD];
    #pragma unroll
    for (int qt = 0; qt < 4; ++qt)
        #pragma unroll
        for (int j = 0; j < KQUAD; ++j) key3[qt][j] = -INFINITY;

    // A-side base pointer for this lane (tile stride = 16 rows * 64 = 1024 shorts)
    const unsigned short* pa = mkT + (size_t)(m_base + l15) * CKDIM + quad * 8;

    // software-pipelined 25-tile loop (double-buffered A frags + asq)
    bf16x8 aF0 = *(const bf16x8*)(pa);
    bf16x8 aF1 = *(const bf16x8*)(pa + 32);
    f32x4  aq  = *(const f32x4*)(asq + m_base + quad * 4);

    for (int t = 0; t < NTILES; ++t) {
        bf16x8 nF0, nF1;
        f32x4  naq;
        if (t + 1 < NTILES) {
            const unsigned short* pn = pa + (size_t)(t + 1) * 1024;
            nF0 = *(const bf16x8*)(pn);
            nF1 = *(const bf16x8*)(pn + 32);
            naq = *(const f32x4*)(asq + m_base + (t + 1) * 16 + quad * 4);
        }
        f32x4 cinit = -0.5f * aq;
        const unsigned int mq = (unsigned int)(m_base + t * 16 + quad * 4);
        #pragma unroll
        for (int qt = 0; qt < 4; ++qt) {
            f32x4 c = cinit;
            c = __builtin_amdgcn_mfma_f32_16x16x32_bf16(aF0, bF[qt][0], c, 0, 0, 0);
            c = __builtin_amdgcn_mfma_f32_16x16x32_bf16(aF1, bF[qt][1], c, 0, 0, 0);
            #pragma unroll
            for (int i = 0; i < 4; ++i) {
                unsigned int kb = (__float_as_uint(c[i]) & 0xFFFF8000u) | (mq + i);
                float kf = __uint_as_float(kb);
                INS3(key3[qt], kf);
            }
        }
        aF0 = nF0; aF1 = nF1; aq = naq;
    }

    #pragma unroll
    for (int qt = 0; qt < 4; ++qt) {
        const int q = q_base + qt * 16 + l15;
        float* dst = pkeys + (size_t)q * KEYSQ + sp * KSPLIT + quad * KQUAD;
        #pragma unroll
        for (int j = 0; j < KQUAD; ++j) dst[j] = key3[qt][j];
    }
}

// ---------------------------------------------------------------------------
// K2: fused select. One wave per query, 4 queries per 256-thread block:
//  (a) lane-local sorted top-8 over strided 972 keys,
//  (b) 32-round tournament pop -> register-resident pool,
//  (c) exact fp32 rescore (contiguous mkTf rows),
//  (d) 64-lane bitonic sort (aff, m) descending -> lanes 0..19 emit
//      softmaxed weights. No LDS, no barriers.
// ---------------------------------------------------------------------------
__global__ __launch_bounds__(256) void k_select(const float* __restrict__ pkeys,
                                                const float* __restrict__ mkTf,
                                                const float* __restrict__ qkTf,
                                                const float* __restrict__ asq,
                                                uint2* __restrict__ qw) {
    const int q    = blockIdx.x * 4 + (threadIdx.x >> 6);
    const int lane = threadIdx.x & 63;

    // (a) local top-8 over 972 keys (16 strided passes, last partial)
    float t[8];
    #pragma unroll
    for (int j = 0; j < 8; ++j) t[j] = -INFINITY;
    const float* src = pkeys + (size_t)q * KEYSQ;
    #pragma unroll
    for (int i = 0; i < 16; ++i) {
        int s = lane + i * 64;
        float v = (s < KEYSQ) ? src[s] : -INFINITY;
        INS8(t, v);
    }

    // (b) tournament: pop global max 32 times
    float mykey = -INFINITY;
    for (int r = 0; r < POOL; ++r) {
        float h = t[0];
        float wm = h;
        #pragma unroll
        for (int off = 32; off; off >>= 1) wm = fmaxf(wm, __shfl_xor(wm, off));
        bool win = (h == wm);
        t[0] = win ? t[1] : t[0];
        t[1] = win ? t[2] : t[1];
        t[2] = win ? t[3] : t[2];
        t[3] = win ? t[4] : t[3];
        t[4] = win ? t[5] : t[4];
        t[5] = win ? t[6] : t[5];
        t[6] = win ? t[7] : t[6];
        t[7] = win ? -INFINITY : t[7];
        if (lane == r) mykey = wm;
    }

    // (c) exact rescore: contiguous 256-B row per candidate; qkTf row uniform
    const int  m_l = (int)(__float_as_uint(mykey) & 0x7FFFu);
    const bool act = (lane < POOL);

    const float4* rm = (const float4*)(mkTf + (size_t)m_l * CKDIM);
    const float4* rq = (const float4*)(qkTf + (size_t)q * CKDIM);
    float dot = 0.f;
    #pragma unroll
    for (int g = 0; g < 16; ++g) {
        float4 a = rm[g];
        float4 b = rq[g];
        dot += a.x * b.x + a.y * b.y + a.z * b.z + a.w * b.w;
    }
    float aff = act ? (2.f * dot - asq[m_l]) * 0.125f : -INFINITY;

    // (d) 64-lane bitonic sort of (aff, m) descending; tie-break smaller m.
    float v  = aff;
    int   mi = m_l;
    #pragma unroll
    for (int k = 2; k <= 64; k <<= 1) {
        #pragma unroll
        for (int j = k >> 1; j > 0; j >>= 1) {
            float ov = __shfl_xor(v, j);
            int   om = __shfl_xor(mi, j);
            const bool asc   = (lane & k) != 0;   // sub-block direction
            const bool lower = (lane & j) == 0;   // lower partner of the pair
            const bool gt    = (v > ov) || (v == ov && mi < om);
            const bool keep  = lower ? (asc ? !gt : gt) : (asc ? gt : !gt);
            if (!keep) { v = ov; mi = om; }
        }
    }

    const float vmax = __shfl(v, 0);
    float e = (lane < TOPK) ? __expf(v - vmax) : 0.f;
    float sum = e;
    #pragma unroll
    for (int off = 32; off; off >>= 1) sum += __shfl_xor(sum, off);

    if (lane < TOPK) {
        unsigned int wbits;
        { union { float f; unsigned int i; } u; u.f = e / sum; wbits = u.i; }
        qw[(size_t)q * TOPK + lane] = make_uint2((unsigned int)mi, wbits);
    }
}

// ---------------------------------------------------------------------------
// K3: readout. Block (512 thr) per oc row; V row bf16 in LDS.
// Streamed staging in 3 batches of 5 uint4 (+tail) keeps live VGPRs ~40
// (the old tA[8]+e0[20]+tB[7] batching held ~100 array regs against the
// launch_bounds-forced 128 cap -> spill risk). qw rows are L2-resident;
// 16 waves/CU of TLP hides their latency without prefetch.
// ---------------------------------------------------------------------------
__global__ __launch_bounds__(512, 4) void k_readout(const float* __restrict__ mv,
                                                    const uint2* __restrict__ qw,
                                                    float* __restrict__ out) {
    __shared__ unsigned short row[M_TOT];   // 64,800 B -> 2 blocks/CU
    const int oc  = blockIdx.x;
    const int tid = threadIdx.x;

    const uint4* s4 = (const uint4*)(mv + (size_t)oc * M_TOT);
    ushort4* d4 = (ushort4*)row;

    // 8100 uint4 total: 15 full strides of 512 + 420 tail
    #pragma unroll
    for (int b = 0; b < 3; ++b) {
        uint4 v[5];
        #pragma unroll
        for (int j = 0; j < 5; ++j) v[j] = s4[tid + (b * 5 + j) * 512];
        #pragma unroll
        for (int j = 0; j < 5; ++j) {
            ushort4 h;
            h.x = f2bf(__uint_as_float(v[j].x));
            h.y = f2bf(__uint_as_float(v[j].y));
            h.z = f2bf(__uint_as_float(v[j].z));
            h.w = f2bf(__uint_as_float(v[j].w));
            d4[tid + (b * 5 + j) * 512] = h;
        }
    }
    if (tid < M_TOT / 4 - 15 * 512) {       // tid < 420
        uint4 v = s4[15 * 512 + tid];
        ushort4 h;
        h.x = f2bf(__uint_as_float(v.x));
        h.y = f2bf(__uint_as_float(v.y));
        h.z = f2bf(__uint_as_float(v.z));
        h.w = f2bf(__uint_as_float(v.w));
        d4[15 * 512 + tid] = h;
    }
    __syncthreads();

    #pragma unroll
    for (int j = 0; j < 4; ++j) {
        int q = tid + j * 512;
        if (q >= QTOT) break;
        const uint2* p = qw + (size_t)q * TOPK;
        float acc = 0.f;
        #pragma unroll
        for (int k = 0; k < TOPK; ++k) {
            uint2 e = p[k];
            acc += __uint_as_float(e.y) * bf2f(row[e.x]);
        }
        out[(size_t)oc * QTOT + q] = acc;
    }
}

// ---------------------------------------------------------------------------
extern "C" void kernel_launch(void* const* d_in, const int* in_sizes, int n_in,
                              void* d_out, int out_size, void* d_ws, size_t ws_size,
                              hipStream_t stream) {
    const float* qk = (const float*)d_in[0];   // [64][1620] fp32
    const float* mk = (const float*)d_in[1];   // [64][32400] fp32
    const float* mv = (const float*)d_in[2];   // [1536][32400] fp32
    float* out = (float*)d_out;                // [1536][1620] fp32

    char* ws = (char*)d_ws;
    float*          asq   = (float*)(ws);                      // 129,600 B
    unsigned short* qkT   = (unsigned short*)(ws + 131072);    // 229,376 B
    unsigned short* mkT   = (unsigned short*)(ws + 360448);    // 4,147,200 B
    float*          mkTf  = (float*)(ws + 4507648);            // 8,294,400 B
    float*          qkTf  = (float*)(ws + 12802048);           // 458,752 B
    float*          pkeys = (float*)(ws + 13260800);           // 1792*972*4 = 6,967,296 B
    uint2*          qw    = (uint2*)(ws + 20228096);           // 259,200 B
    // total ~= 20.5 MB

    k_prep     <<<dim3((M_TOT + QPAD + 255) / 256), dim3(256), 0, stream>>>(
                   mk, qk, asq, mkT, mkTf, qkT, qkTf);
    k_topk_mfma<<<dim3(7, NSPLIT),                  dim3(256), 0, stream>>>(mkT, qkT, asq, pkeys);
    k_select   <<<dim3(QTOT / 4),                   dim3(256), 0, stream>>>(pkeys, mkTf, qkTf, asq, qw);
    k_readout  <<<dim3(OCDIM),                      dim3(512), 0, stream>>>(mv, qw, out);
}